// Round 1
// baseline (489.966 us; speedup 1.0000x reference)
//
#include <hip/hip_runtime.h>
#include <cstdint>
#include <cstddef>

#define HIDDEN 256
#define NHEADS 8
#define HDIM 32
#define KLEN 8192
#define BATCH 32
#define NCHUNK 16
#define CHUNK (KLEN / NCHUNK)   // 512
#define LN_EPS 1e-5f

// ---------------- workspace layout (float offsets) ----------------
#define OFF_QT   ((size_t)0)
#define SZ_QT    ((size_t)2*BATCH*NHEADS*HIDDEN)          // 131072
#define OFF_SC   (OFF_QT + SZ_QT)
#define SZ_SC    ((size_t)2*BATCH*KLEN*NHEADS)            // 4194304
#define OFF_TAU  (OFF_SC + SZ_SC)
#define SZ_TAU   ((size_t)2*BATCH*NHEADS)                 // 512
#define OFF_UP   (OFF_TAU + SZ_TAU)
#define SZ_UP    ((size_t)2*BATCH*NCHUNK*NHEADS*HIDDEN)   // 2097152
#define OFF_COMB (OFF_UP + SZ_UP)
#define SZ_COMB  ((size_t)BATCH*2*HIDDEN)                 // 16384

// K1: qh = z_gene @ Wq^T (per b), then qtilde[m][b][n][h] = alpha*0.5 * sum_d qh[n,d]*Wk_m[n*32+d, h]
__global__ void k_prep(const float* __restrict__ zg, const float* __restrict__ Wq,
                       const float* __restrict__ Wk0, const float* __restrict__ Wk1,
                       const float* __restrict__ log_temp, float* __restrict__ qt) {
    int b = blockIdx.x, t = threadIdx.x;
    __shared__ float z[HIDDEN];
    __shared__ float qh[HIDDEN];
    z[t] = zg[(size_t)b*HIDDEN + t];
    __syncthreads();
    // qh[t], t = n*32 + d
    const float4* wr4 = (const float4*)(Wq + (size_t)t*HIDDEN);
    const float4* z4 = (const float4*)z;
    float acc = 0.f;
    #pragma unroll 8
    for (int i = 0; i < HIDDEN/4; ++i) {
        float4 w = wr4[i], zz = z4[i];
        acc += w.x*zz.x + w.y*zz.y + w.z*zz.z + w.w*zz.w;
    }
    qh[t] = acc;
    __syncthreads();
    float alpha = 0.5f * rsqrtf((float)HDIM) * __expf(log_temp[0]);
    for (int m = 0; m < 2; ++m) {
        const float* Wk = m ? Wk1 : Wk0;
        for (int n = 0; n < NHEADS; ++n) {
            float a = 0.f;
            #pragma unroll 8
            for (int d = 0; d < HDIM; ++d) {
                a += qh[n*HDIM + d] * Wk[(size_t)(n*HDIM + d)*HIDDEN + t];
            }
            qt[(((size_t)m*BATCH + b)*NHEADS + n)*HIDDEN + t] = a * alpha;
        }
    }
}

// K2: z-scores: sc[m][b][k][n] = qtilde[m][b][n][:] . kv_m[b][k][:]
__global__ void __launch_bounds__(256) k_scores(const float* __restrict__ kv0,
                                                const float* __restrict__ kv1,
                                                const float* __restrict__ qt,
                                                float* __restrict__ sc) {
    int bid = blockIdx.x;              // BATCH * 2 * NCHUNK
    int chunk = bid % NCHUNK;
    int m = (bid / NCHUNK) & 1;
    int b = bid / (2*NCHUNK);
    int t = threadIdx.x;
    __shared__ float lq[NHEADS*260];   // padded stride 260 (bank-conflict-free)
    const float* qtg = qt + ((size_t)m*BATCH + b)*NHEADS*HIDDEN;
    #pragma unroll
    for (int i = 0; i < 8; ++i) {
        int j = t + i*256;
        lq[(j >> 8)*260 + (j & 255)] = qtg[j];
    }
    __syncthreads();
    const float* kv = (m ? kv1 : kv0) + (size_t)b*KLEN*HIDDEN;
    int n = t & 7;
    const float4* q4 = (const float4*)(lq + n*260);
    float* out = sc + ((size_t)m*BATCH + b)*KLEN*NHEADS;
    for (int step = 0; step < CHUNK/32; ++step) {
        int r = chunk*CHUNK + step*32 + (t >> 3);
        const float4* kv4 = (const float4*)(kv + (size_t)r*HIDDEN);
        float acc = 0.f;
        #pragma unroll 8
        for (int i = 0; i < HIDDEN/4; ++i) {
            float4 a = kv4[i], qq = q4[i];
            acc += a.x*qq.x + a.y*qq.y + a.z*qq.z + a.w*qq.w;
        }
        out[(size_t)r*NHEADS + n] = acc;
    }
}

// K3: entmax tau by bisection: find tau with sum max(z-tau,0)^2 = 1
__global__ void __launch_bounds__(256) k_entmax(const float* __restrict__ sc,
                                                float* __restrict__ tau) {
    int bid = blockIdx.x;              // m*256 + b*8 + n
    int n = bid & 7, b = (bid >> 3) & 31, m = bid >> 8;
    int t = threadIdx.x;
    __shared__ float zs[KLEN];
    __shared__ float red[4];
    const float* src = sc + ((size_t)m*BATCH + b)*KLEN*NHEADS + n;
    float mx = -1e30f;
    #pragma unroll
    for (int i = 0; i < KLEN/256; ++i) {
        float v = src[(size_t)(t + i*256)*NHEADS];
        zs[t + i*256] = v;
        mx = fmaxf(mx, v);
    }
    for (int off = 32; off; off >>= 1) mx = fmaxf(mx, __shfl_xor(mx, off));
    if ((t & 63) == 0) red[t >> 6] = mx;
    __syncthreads();
    mx = fmaxf(fmaxf(red[0], red[1]), fmaxf(red[2], red[3]));
    __syncthreads();
    float lo = mx - 1.0f, hi = mx;
    for (int it = 0; it < 30; ++it) {
        float tm = 0.5f*(lo + hi);
        float s = 0.f;
        #pragma unroll
        for (int i = 0; i < KLEN/256; ++i) {
            float d = zs[t + i*256] - tm;
            d = fmaxf(d, 0.f);
            s += d*d;
        }
        for (int off = 32; off; off >>= 1) s += __shfl_xor(s, off);
        if ((t & 63) == 0) red[t >> 6] = s;
        __syncthreads();
        s = red[0] + red[1] + red[2] + red[3];
        __syncthreads();
        if (s >= 1.0f) lo = tm; else hi = tm;
    }
    if (t == 0) tau[bid] = 0.5f*(lo + hi);
}

// K4: u[m][b][n][h] partial sums per chunk: u[n][h] = sum_k p[n][k]*kv[k][h]
__global__ void __launch_bounds__(256) k_ctxsum(const float* __restrict__ kv0,
                                                const float* __restrict__ kv1,
                                                const float* __restrict__ sc,
                                                const float* __restrict__ tau,
                                                float* __restrict__ upart) {
    int bid = blockIdx.x;
    int chunk = bid % NCHUNK;
    int m = (bid / NCHUNK) & 1;
    int b = bid / (2*NCHUNK);
    int t = threadIdx.x;
    const float* kv = (m ? kv1 : kv0) + (size_t)b*KLEN*HIDDEN;
    const float* zrow = sc + ((size_t)m*BATCH + b)*KLEN*NHEADS;
    float tv[8];
    #pragma unroll
    for (int n = 0; n < 8; ++n) tv[n] = tau[((size_t)m*BATCH + b)*NHEADS + n];
    float u[8] = {0.f,0.f,0.f,0.f,0.f,0.f,0.f,0.f};
    for (int kk = 0; kk < CHUNK; ++kk) {
        int k = chunk*CHUNK + kk;
        const float4* zp = (const float4*)(zrow + (size_t)k*NHEADS);
        float4 za = zp[0], zb = zp[1];
        float kvv = kv[(size_t)k*HIDDEN + t];
        float d;
        d = fmaxf(za.x - tv[0], 0.f); u[0] = fmaf(d*d, kvv, u[0]);
        d = fmaxf(za.y - tv[1], 0.f); u[1] = fmaf(d*d, kvv, u[1]);
        d = fmaxf(za.z - tv[2], 0.f); u[2] = fmaf(d*d, kvv, u[2]);
        d = fmaxf(za.w - tv[3], 0.f); u[3] = fmaf(d*d, kvv, u[3]);
        d = fmaxf(zb.x - tv[4], 0.f); u[4] = fmaf(d*d, kvv, u[4]);
        d = fmaxf(zb.y - tv[5], 0.f); u[5] = fmaf(d*d, kvv, u[5]);
        d = fmaxf(zb.z - tv[6], 0.f); u[6] = fmaf(d*d, kvv, u[6]);
        d = fmaxf(zb.w - tv[7], 0.f); u[7] = fmaf(d*d, kvv, u[7]);
    }
    float* up = upart + (((size_t)m*BATCH + b)*NCHUNK + chunk)*NHEADS*HIDDEN;
    #pragma unroll
    for (int n = 0; n < 8; ++n) up[(size_t)n*HIDDEN + t] = u[n];
}

// K5: reduce chunks, project through Wv, apply modality softmax weight, write combined
__global__ void k_ctx(const float* __restrict__ upart, const float* __restrict__ Wv0,
                      const float* __restrict__ Wv1, const float* __restrict__ mlogits,
                      float* __restrict__ comb) {
    int b = blockIdx.x, t = threadIdx.x;
    __shared__ float ul[NHEADS*260];
    float l0 = mlogits[0], l1 = mlogits[1];
    float mxl = fmaxf(l0, l1);
    float e0 = __expf(l0 - mxl), e1 = __expf(l1 - mxl);
    float w0 = e0/(e0 + e1), w1 = e1/(e0 + e1);
    for (int m = 0; m < 2; ++m) {
        const float* Wv = m ? Wv1 : Wv0;
        float wm = m ? w1 : w0;
        __syncthreads();
        for (int n = 0; n < NHEADS; ++n) {
            float s = 0.f;
            const float* up = upart + ((size_t)m*BATCH + b)*NCHUNK*NHEADS*HIDDEN
                              + (size_t)n*HIDDEN + t;
            #pragma unroll
            for (int c = 0; c < NCHUNK; ++c) s += up[(size_t)c*NHEADS*HIDDEN];
            ul[n*260 + t] = s;
        }
        __syncthreads();
        int n = t >> 5;   // t = n*32 + d
        const float4* wr4 = (const float4*)(Wv + (size_t)t*HIDDEN);
        const float4* uu4 = (const float4*)(ul + n*260);
        float acc = 0.f;
        #pragma unroll 8
        for (int i = 0; i < HIDDEN/4; ++i) {
            float4 w = wr4[i], uu = uu4[i];
            acc += w.x*uu.x + w.y*uu.y + w.z*uu.z + w.w*uu.w;
        }
        comb[(size_t)b*(2*HIDDEN) + (size_t)m*HIDDEN + t] = acc * wm;
    }
}

// K6: out = LayerNorm(comb @ Wout^T + b_out + z_gene)
__global__ void k_out(const float* __restrict__ comb, const float* __restrict__ Wout,
                      const float* __restrict__ bout, const float* __restrict__ zg,
                      const float* __restrict__ gamma, const float* __restrict__ beta,
                      float* __restrict__ out) {
    int b = blockIdx.x, t = threadIdx.x;
    __shared__ float cl[2*HIDDEN];
    __shared__ float red[4];
    cl[t] = comb[(size_t)b*512 + t];
    cl[t + 256] = comb[(size_t)b*512 + 256 + t];
    __syncthreads();
    float acc = bout[t] + zg[(size_t)b*HIDDEN + t];
    const float4* wr4 = (const float4*)(Wout + (size_t)t*512);
    const float4* cl4 = (const float4*)cl;
    #pragma unroll 8
    for (int i = 0; i < 512/4; ++i) {
        float4 w = wr4[i], c = cl4[i];
        acc += w.x*c.x + w.y*c.y + w.z*c.z + w.w*c.w;
    }
    float s = acc;
    for (int off = 32; off; off >>= 1) s += __shfl_xor(s, off);
    if ((t & 63) == 0) red[t >> 6] = s;
    __syncthreads();
    float mu = (red[0] + red[1] + red[2] + red[3]) * (1.0f/HIDDEN);
    __syncthreads();
    float dv = acc - mu;
    float vs = dv*dv;
    for (int off = 32; off; off >>= 1) vs += __shfl_xor(vs, off);
    if ((t & 63) == 0) red[t >> 6] = vs;
    __syncthreads();
    float var = (red[0] + red[1] + red[2] + red[3]) * (1.0f/HIDDEN);
    out[(size_t)b*HIDDEN + t] = dv * rsqrtf(var + LN_EPS) * gamma[t] + beta[t];
}

extern "C" void kernel_launch(void* const* d_in, const int* in_sizes, int n_in,
                              void* d_out, int out_size, void* d_ws, size_t ws_size,
                              hipStream_t stream) {
    const float* zg    = (const float*)d_in[0];
    const float* cpg   = (const float*)d_in[1];
    const float* mir   = (const float*)d_in[2];
    const float* Wq    = (const float*)d_in[3];
    const float* Wk0   = (const float*)d_in[4];
    const float* Wv0   = (const float*)d_in[5];
    const float* Wk1   = (const float*)d_in[6];
    const float* Wv1   = (const float*)d_in[7];
    const float* Wout  = (const float*)d_in[8];
    const float* bout  = (const float*)d_in[9];
    const float* gam   = (const float*)d_in[10];
    const float* bet   = (const float*)d_in[11];
    const float* mlog  = (const float*)d_in[12];
    const float* ltemp = (const float*)d_in[13];

    float* ws   = (float*)d_ws;
    float* qt   = ws + OFF_QT;
    float* sc   = ws + OFF_SC;
    float* tau  = ws + OFF_TAU;
    float* up   = ws + OFF_UP;
    float* comb = ws + OFF_COMB;
    float* out  = (float*)d_out;

    hipLaunchKernelGGL(k_prep,   dim3(BATCH),            dim3(256), 0, stream,
                       zg, Wq, Wk0, Wk1, ltemp, qt);
    hipLaunchKernelGGL(k_scores, dim3(BATCH*2*NCHUNK),   dim3(256), 0, stream,
                       cpg, mir, qt, sc);
    hipLaunchKernelGGL(k_entmax, dim3(2*BATCH*NHEADS),   dim3(256), 0, stream,
                       sc, tau);
    hipLaunchKernelGGL(k_ctxsum, dim3(BATCH*2*NCHUNK),   dim3(256), 0, stream,
                       cpg, mir, sc, tau, up);
    hipLaunchKernelGGL(k_ctx,    dim3(BATCH),            dim3(256), 0, stream,
                       up, Wv0, Wv1, mlog, comb);
    hipLaunchKernelGGL(k_out,    dim3(BATCH),            dim3(256), 0, stream,
                       comb, Wout, bout, zg, gam, bet, out);
}

// Round 2
// 322.026 us; speedup vs baseline: 1.5215x; 1.5215x over previous
//
#include <hip/hip_runtime.h>
#include <cstdint>
#include <cstddef>

#define HIDDEN 256
#define NHEADS 8
#define HDIM 32
#define KLEN 8192
#define BATCH 32
#define NCHUNK 16
#define CHUNK (KLEN / NCHUNK)   // 512
#define LN_EPS 1e-5f

// ---------------- workspace layout (float offsets) ----------------
#define OFF_QT   ((size_t)0)
#define SZ_QT    ((size_t)2*BATCH*NHEADS*HIDDEN)          // 131072
#define OFF_SC   (OFF_QT + SZ_QT)
#define SZ_SC    ((size_t)2*BATCH*KLEN*NHEADS)            // 4194304
#define OFF_TAU  (OFF_SC + SZ_SC)
#define SZ_TAU   ((size_t)2*BATCH*NHEADS)                 // 512
#define OFF_UP   (OFF_TAU + SZ_TAU)
#define SZ_UP    ((size_t)2*BATCH*NCHUNK*NHEADS*HIDDEN)   // 2097152
#define OFF_COMB (OFF_UP + SZ_UP)
#define SZ_COMB  ((size_t)BATCH*2*HIDDEN)                 // 16384

// K1: qh = z_gene @ Wq^T (per b), then qtilde[m][b][n][h] = alpha * sum_d qh[n,d]*Wk_m[n*32+d, h]
__global__ void k_prep(const float* __restrict__ zg, const float* __restrict__ Wq,
                       const float* __restrict__ Wk0, const float* __restrict__ Wk1,
                       const float* __restrict__ log_temp, float* __restrict__ qt) {
    int b = blockIdx.x, t = threadIdx.x;
    __shared__ float z[HIDDEN];
    __shared__ float qh[HIDDEN];
    z[t] = zg[(size_t)b*HIDDEN + t];
    __syncthreads();
    const float4* wr4 = (const float4*)(Wq + (size_t)t*HIDDEN);
    const float4* z4 = (const float4*)z;
    float acc = 0.f;
    #pragma unroll 8
    for (int i = 0; i < HIDDEN/4; ++i) {
        float4 w = wr4[i], zz = z4[i];
        acc += w.x*zz.x + w.y*zz.y + w.z*zz.z + w.w*zz.w;
    }
    qh[t] = acc;
    __syncthreads();
    float alpha = 0.5f * rsqrtf((float)HDIM) * __expf(log_temp[0]);
    for (int m = 0; m < 2; ++m) {
        const float* Wk = m ? Wk1 : Wk0;
        for (int n = 0; n < NHEADS; ++n) {
            float a = 0.f;
            #pragma unroll 8
            for (int d = 0; d < HDIM; ++d) {
                a += qh[n*HDIM + d] * Wk[(size_t)(n*HDIM + d)*HIDDEN + t];
            }
            qt[(((size_t)m*BATCH + b)*NHEADS + n)*HIDDEN + t] = a * alpha;
        }
    }
}

// K2 v2: sc[m][b][k][n] = qtilde[m][b][n][:] . kv_m[b][k][:]
// Each 8-lane group: 2 rows per pass, lane owns a 32-float segment (unique, coalesced).
// q-fragments from LDS (broadcast, conflict-free). Transposing shfl reduction:
// lane seg ends holding head==seg.
__global__ void __launch_bounds__(256) k_scores(const float* __restrict__ kv0,
                                                const float* __restrict__ kv1,
                                                const float* __restrict__ qt,
                                                float* __restrict__ sc) {
    int bid = blockIdx.x;              // BATCH * 2 * NCHUNK
    int chunk = bid % NCHUNK;
    int m = (bid / NCHUNK) & 1;
    int b = bid / (2*NCHUNK);
    int t = threadIdx.x;
    int wave = t >> 6;
    int g    = (t >> 3) & 7;           // group within wave
    int seg  = t & 7;                  // 32-float segment / final head id
    __shared__ float lq[NHEADS*260];   // padded stride 260
    const float* qtg = qt + ((size_t)m*BATCH + b)*NHEADS*HIDDEN;
    #pragma unroll
    for (int i = 0; i < 8; ++i) {
        int j = t + i*256;
        lq[(j >> 8)*260 + (j & 255)] = qtg[j];
    }
    __syncthreads();
    const float* kv = (m ? kv1 : kv0) + (size_t)b*KLEN*HIDDEN;
    const float4* kv4 = (const float4*)kv;
    float* out = sc + ((size_t)m*BATCH + b)*KLEN*NHEADS;
    int b0 = seg & 1, b1 = (seg >> 1) & 1, b2 = (seg >> 2) & 1;

    int rowbase = chunk*CHUNK + wave*128;
    for (int pass = 0; pass < 8; ++pass) {
        size_t r0 = (size_t)rowbase + pass*16 + g*2;
        size_t r1 = r0 + 1;
        float4 kva[8], kvb[8];
        #pragma unroll
        for (int i = 0; i < 8; ++i) kva[i] = kv4[r0*64 + i*8 + seg];
        #pragma unroll
        for (int i = 0; i < 8; ++i) kvb[i] = kv4[r1*64 + i*8 + seg];
        float acc0[8], acc1[8];
        #pragma unroll
        for (int n = 0; n < 8; ++n) { acc0[n] = 0.f; acc1[n] = 0.f; }
        #pragma unroll
        for (int n = 0; n < 8; ++n) {
            const float4* qn4 = (const float4*)(lq + n*260);
            #pragma unroll
            for (int i = 0; i < 8; ++i) {
                float4 q = qn4[i*8 + seg];
                acc0[n] += kva[i].x*q.x + kva[i].y*q.y + kva[i].z*q.z + kva[i].w*q.w;
                acc1[n] += kvb[i].x*q.x + kvb[i].y*q.y + kvb[i].z*q.z + kvb[i].w*q.w;
            }
        }
        // transposing reduce across the 8 lanes of the group
        float w0[4], w1[4];
        #pragma unroll
        for (int j = 0; j < 4; ++j) {
            float k0 = b0 ? acc0[2*j+1] : acc0[2*j];
            float s0 = b0 ? acc0[2*j]   : acc0[2*j+1];
            w0[j] = k0 + __shfl_xor(s0, 1);
            float k1 = b0 ? acc1[2*j+1] : acc1[2*j];
            float s1 = b0 ? acc1[2*j]   : acc1[2*j+1];
            w1[j] = k1 + __shfl_xor(s1, 1);
        }
        float x0[2], x1[2];
        #pragma unroll
        for (int j = 0; j < 2; ++j) {
            float k0 = b1 ? w0[2*j+1] : w0[2*j];
            float s0 = b1 ? w0[2*j]   : w0[2*j+1];
            x0[j] = k0 + __shfl_xor(s0, 2);
            float k1 = b1 ? w1[2*j+1] : w1[2*j];
            float s1 = b1 ? w1[2*j]   : w1[2*j+1];
            x1[j] = k1 + __shfl_xor(s1, 2);
        }
        float ka = b2 ? x0[1] : x0[0];
        float sa = b2 ? x0[0] : x0[1];
        float y0 = ka + __shfl_xor(sa, 4);
        float kb = b2 ? x1[1] : x1[0];
        float sb = b2 ? x1[0] : x1[1];
        float y1 = kb + __shfl_xor(sb, 4);
        out[r0*8 + seg] = y0;
        out[r1*8 + seg] = y1;
    }
}

// K3 v2: entmax tau by bisection (vectorized LDS reads)
__global__ void __launch_bounds__(256) k_entmax(const float* __restrict__ sc,
                                                float* __restrict__ tau) {
    int bid = blockIdx.x;              // m*256 + b*8 + n
    int n = bid & 7, b = (bid >> 3) & 31, m = bid >> 8;
    int t = threadIdx.x;
    __shared__ float zs[KLEN];
    __shared__ float red[4];
    const float* src = sc + ((size_t)m*BATCH + b)*KLEN*NHEADS + n;
    float mx = -1e30f;
    #pragma unroll
    for (int i = 0; i < KLEN/256; ++i) {
        float v = src[(size_t)(t + i*256)*NHEADS];
        zs[t + i*256] = v;
        mx = fmaxf(mx, v);
    }
    for (int off = 32; off; off >>= 1) mx = fmaxf(mx, __shfl_xor(mx, off));
    if ((t & 63) == 0) red[t >> 6] = mx;
    __syncthreads();
    mx = fmaxf(fmaxf(red[0], red[1]), fmaxf(red[2], red[3]));
    __syncthreads();
    const float4* z4 = (const float4*)zs;
    float lo = mx - 1.0f, hi = mx;
    for (int it = 0; it < 30; ++it) {
        float tm = 0.5f*(lo + hi);
        float s = 0.f;
        #pragma unroll
        for (int i = 0; i < 8; ++i) {
            float4 zz = z4[t + i*256];
            float d;
            d = fmaxf(zz.x - tm, 0.f); s = fmaf(d, d, s);
            d = fmaxf(zz.y - tm, 0.f); s = fmaf(d, d, s);
            d = fmaxf(zz.z - tm, 0.f); s = fmaf(d, d, s);
            d = fmaxf(zz.w - tm, 0.f); s = fmaf(d, d, s);
        }
        for (int off = 32; off; off >>= 1) s += __shfl_xor(s, off);
        if ((t & 63) == 0) red[t >> 6] = s;
        __syncthreads();
        s = red[0] + red[1] + red[2] + red[3];
        __syncthreads();
        if (s >= 1.0f) lo = tm; else hi = tm;
    }
    if (t == 0) tau[bid] = 0.5f*(lo + hi);
}

// K4 v2: u[m][b][n][h] partial sums per chunk. Lane owns 4 h-columns (float4),
// one k per wave per step; p[n] computed once per (k,head); 32-reg accumulator.
__global__ void __launch_bounds__(256) k_ctxsum(const float* __restrict__ kv0,
                                                const float* __restrict__ kv1,
                                                const float* __restrict__ sc,
                                                const float* __restrict__ tau,
                                                float* __restrict__ upart) {
    int bid = blockIdx.x;
    int chunk = bid % NCHUNK;
    int m = (bid / NCHUNK) & 1;
    int b = bid / (2*NCHUNK);
    int t = threadIdx.x;
    int wave = t >> 6, lane = t & 63;
    const float* kv = (m ? kv1 : kv0) + (size_t)b*KLEN*HIDDEN;
    const float4* kv4 = (const float4*)kv;
    const float* zrow = sc + ((size_t)m*BATCH + b)*KLEN*NHEADS;
    const float4* zrow4 = (const float4*)zrow;
    float tv[8];
    #pragma unroll
    for (int n = 0; n < 8; ++n) tv[n] = tau[((size_t)m*BATCH + b)*NHEADS + n];
    float acc[8][4];
    #pragma unroll
    for (int n = 0; n < 8; ++n)
        #pragma unroll
        for (int c = 0; c < 4; ++c) acc[n][c] = 0.f;

    #pragma unroll 2
    for (int kk = wave; kk < CHUNK; kk += 4) {
        size_t k = (size_t)chunk*CHUNK + kk;
        float4 kvv = kv4[k*64 + lane];
        float4 za = zrow4[k*2], zb = zrow4[k*2 + 1];
        float p[8], d;
        d = fmaxf(za.x - tv[0], 0.f); p[0] = d*d;
        d = fmaxf(za.y - tv[1], 0.f); p[1] = d*d;
        d = fmaxf(za.z - tv[2], 0.f); p[2] = d*d;
        d = fmaxf(za.w - tv[3], 0.f); p[3] = d*d;
        d = fmaxf(zb.x - tv[4], 0.f); p[4] = d*d;
        d = fmaxf(zb.y - tv[5], 0.f); p[5] = d*d;
        d = fmaxf(zb.z - tv[6], 0.f); p[6] = d*d;
        d = fmaxf(zb.w - tv[7], 0.f); p[7] = d*d;
        #pragma unroll
        for (int n = 0; n < 8; ++n) {
            acc[n][0] = fmaf(p[n], kvv.x, acc[n][0]);
            acc[n][1] = fmaf(p[n], kvv.y, acc[n][1]);
            acc[n][2] = fmaf(p[n], kvv.z, acc[n][2]);
            acc[n][3] = fmaf(p[n], kvv.w, acc[n][3]);
        }
    }
    // cross-wave reduce via LDS
    __shared__ float redls[4*NHEADS*HIDDEN];    // 32 KB
    float4* red4 = (float4*)redls;
    #pragma unroll
    for (int n = 0; n < 8; ++n) {
        float4 v; v.x = acc[n][0]; v.y = acc[n][1]; v.z = acc[n][2]; v.w = acc[n][3];
        red4[((size_t)wave*8 + n)*64 + lane] = v;
    }
    __syncthreads();
    float* up = upart + (((size_t)m*BATCH + b)*NCHUNK + chunk)*NHEADS*HIDDEN;
    int n = t >> 5, hq = (t & 31)*2;   // two float4s per thread
    #pragma unroll
    for (int j = 0; j < 2; ++j) {
        float4 s = red4[((size_t)0*8 + n)*64 + hq + j];
        #pragma unroll
        for (int w = 1; w < 4; ++w) {
            float4 v = red4[((size_t)w*8 + n)*64 + hq + j];
            s.x += v.x; s.y += v.y; s.z += v.z; s.w += v.w;
        }
        ((float4*)(up + (size_t)n*HIDDEN))[hq + j] = s;
    }
}

// K5: reduce chunks, project through Wv, apply modality softmax weight, write combined
__global__ void k_ctx(const float* __restrict__ upart, const float* __restrict__ Wv0,
                      const float* __restrict__ Wv1, const float* __restrict__ mlogits,
                      float* __restrict__ comb) {
    int b = blockIdx.x, t = threadIdx.x;
    __shared__ float ul[NHEADS*260];
    float l0 = mlogits[0], l1 = mlogits[1];
    float mxl = fmaxf(l0, l1);
    float e0 = __expf(l0 - mxl), e1 = __expf(l1 - mxl);
    float w0 = e0/(e0 + e1), w1 = e1/(e0 + e1);
    for (int m = 0; m < 2; ++m) {
        const float* Wv = m ? Wv1 : Wv0;
        float wm = m ? w1 : w0;
        __syncthreads();
        for (int n = 0; n < NHEADS; ++n) {
            float s = 0.f;
            const float* up = upart + ((size_t)m*BATCH + b)*NCHUNK*NHEADS*HIDDEN
                              + (size_t)n*HIDDEN + t;
            #pragma unroll
            for (int c = 0; c < NCHUNK; ++c) s += up[(size_t)c*NHEADS*HIDDEN];
            ul[n*260 + t] = s;
        }
        __syncthreads();
        int n = t >> 5;   // t = n*32 + d
        const float4* wr4 = (const float4*)(Wv + (size_t)t*HIDDEN);
        const float4* uu4 = (const float4*)(ul + n*260);
        float acc = 0.f;
        #pragma unroll 8
        for (int i = 0; i < HIDDEN/4; ++i) {
            float4 w = wr4[i], uu = uu4[i];
            acc += w.x*uu.x + w.y*uu.y + w.z*uu.z + w.w*uu.w;
        }
        comb[(size_t)b*(2*HIDDEN) + (size_t)m*HIDDEN + t] = acc * wm;
    }
}

// K6: out = LayerNorm(comb @ Wout^T + b_out + z_gene)
__global__ void k_out(const float* __restrict__ comb, const float* __restrict__ Wout,
                      const float* __restrict__ bout, const float* __restrict__ zg,
                      const float* __restrict__ gamma, const float* __restrict__ beta,
                      float* __restrict__ out) {
    int b = blockIdx.x, t = threadIdx.x;
    __shared__ float cl[2*HIDDEN];
    __shared__ float red[4];
    cl[t] = comb[(size_t)b*512 + t];
    cl[t + 256] = comb[(size_t)b*512 + 256 + t];
    __syncthreads();
    float acc = bout[t] + zg[(size_t)b*HIDDEN + t];
    const float4* wr4 = (const float4*)(Wout + (size_t)t*512);
    const float4* cl4 = (const float4*)cl;
    #pragma unroll 8
    for (int i = 0; i < 512/4; ++i) {
        float4 w = wr4[i], c = cl4[i];
        acc += w.x*c.x + w.y*c.y + w.z*c.z + w.w*c.w;
    }
    float s = acc;
    for (int off = 32; off; off >>= 1) s += __shfl_xor(s, off);
    if ((t & 63) == 0) red[t >> 6] = s;
    __syncthreads();
    float mu = (red[0] + red[1] + red[2] + red[3]) * (1.0f/HIDDEN);
    __syncthreads();
    float dv = acc - mu;
    float vs = dv*dv;
    for (int off = 32; off; off >>= 1) vs += __shfl_xor(vs, off);
    if ((t & 63) == 0) red[t >> 6] = vs;
    __syncthreads();
    float var = (red[0] + red[1] + red[2] + red[3]) * (1.0f/HIDDEN);
    out[(size_t)b*HIDDEN + t] = dv * rsqrtf(var + LN_EPS) * gamma[t] + beta[t];
}

extern "C" void kernel_launch(void* const* d_in, const int* in_sizes, int n_in,
                              void* d_out, int out_size, void* d_ws, size_t ws_size,
                              hipStream_t stream) {
    const float* zg    = (const float*)d_in[0];
    const float* cpg   = (const float*)d_in[1];
    const float* mir   = (const float*)d_in[2];
    const float* Wq    = (const float*)d_in[3];
    const float* Wk0   = (const float*)d_in[4];
    const float* Wv0   = (const float*)d_in[5];
    const float* Wk1   = (const float*)d_in[6];
    const float* Wv1   = (const float*)d_in[7];
    const float* Wout  = (const float*)d_in[8];
    const float* bout  = (const float*)d_in[9];
    const float* gam   = (const float*)d_in[10];
    const float* bet   = (const float*)d_in[11];
    const float* mlog  = (const float*)d_in[12];
    const float* ltemp = (const float*)d_in[13];

    float* ws   = (float*)d_ws;
    float* qt   = ws + OFF_QT;
    float* sc   = ws + OFF_SC;
    float* tau  = ws + OFF_TAU;
    float* up   = ws + OFF_UP;
    float* comb = ws + OFF_COMB;
    float* out  = (float*)d_out;

    hipLaunchKernelGGL(k_prep,   dim3(BATCH),            dim3(256), 0, stream,
                       zg, Wq, Wk0, Wk1, ltemp, qt);
    hipLaunchKernelGGL(k_scores, dim3(BATCH*2*NCHUNK),   dim3(256), 0, stream,
                       cpg, mir, qt, sc);
    hipLaunchKernelGGL(k_entmax, dim3(2*BATCH*NHEADS),   dim3(256), 0, stream,
                       sc, tau);
    hipLaunchKernelGGL(k_ctxsum, dim3(BATCH*2*NCHUNK),   dim3(256), 0, stream,
                       cpg, mir, sc, tau, up);
    hipLaunchKernelGGL(k_ctx,    dim3(BATCH),            dim3(256), 0, stream,
                       up, Wv0, Wv1, mlog, comb);
    hipLaunchKernelGGL(k_out,    dim3(BATCH),            dim3(256), 0, stream,
                       comb, Wout, bout, zg, gam, bet, out);
}